// Round 1
// 1042.184 us; speedup vs baseline: 1.3884x; 1.3884x over previous
//
#include <hip/hip_runtime.h>
#include <hip/hip_bf16.h>

// Problem dims
#define B_SZ   8192
#define IN_SZ  1024
#define H1_SZ  2048
#define H2_SZ  2048
#define OUT_SZ 1024
#define NP     8

typedef __bf16 bf16x8 __attribute__((ext_vector_type(8)));
typedef float  f32x4  __attribute__((ext_vector_type(4)));

__device__ __forceinline__ void async_ld16(const void* g, void* l) {
    __builtin_amdgcn_global_load_lds(
        (const __attribute__((address_space(1))) unsigned int*)g,
        (__attribute__((address_space(3))) unsigned int*)l,
        16, 0, 0);
}

__device__ __forceinline__ float bfbits_to_f(unsigned int u) {
    union { unsigned int i; float f; } c;
    c.i = u << 16;
    return c.f;
}

// in [K][N] f32  ->  out [N][K] bf16  (transposed cast, so GEMM B-operand is K-contiguous)
__global__ void transpose_cast_k(const float* __restrict__ in, __hip_bfloat16* __restrict__ out,
                                 int K, int N) {
    __shared__ float tile[32][33];
    int n0 = blockIdx.x * 32, k0 = blockIdx.y * 32;
    int tx = threadIdx.x, ty = threadIdx.y;  // 32 x 8
#pragma unroll
    for (int j = 0; j < 4; ++j)
        tile[ty + j * 8][tx] = in[(size_t)(k0 + ty + j * 8) * N + (n0 + tx)];
    __syncthreads();
#pragma unroll
    for (int j = 0; j < 4; ++j) {
        int nn = ty + j * 8;
        out[(size_t)(n0 + nn) * K + (k0 + tx)] = __float2bfloat16(tile[tx][nn]);
    }
}

// probs[b,:] = softmax(in[b,:] @ S + sb)   — one wave per row
template <typename T>
__global__ void selector_k(const T* __restrict__ in, const float* __restrict__ S,
                           const float* __restrict__ sb, float* __restrict__ probs, int K) {
    int row  = blockIdx.x * blockDim.y + threadIdx.y;
    int lane = threadIdx.x;
    float acc[NP];
#pragma unroll
    for (int p = 0; p < NP; ++p) acc[p] = 0.f;
    const T* xr = in + (size_t)row * K;
    for (int k = lane; k < K; k += 64) {
        float xv;
        if constexpr (sizeof(T) == 2) xv = __bfloat162float(xr[k]);
        else                          xv = (float)xr[k];
        const float* sr = S + (size_t)k * NP;
#pragma unroll
        for (int p = 0; p < NP; ++p) acc[p] += xv * sr[p];
    }
#pragma unroll
    for (int p = 0; p < NP; ++p)
#pragma unroll
        for (int off = 32; off > 0; off >>= 1)
            acc[p] += __shfl_down(acc[p], off, 64);
    if (lane == 0) {
        float v[NP], m = -1e30f;
#pragma unroll
        for (int p = 0; p < NP; ++p) { v[p] = acc[p] + sb[p]; m = fmaxf(m, v[p]); }
        float s = 0.f;
#pragma unroll
        for (int p = 0; p < NP; ++p) { v[p] = expf(v[p] - m); s += v[p]; }
        float inv = 1.f / s;
#pragma unroll
        for (int p = 0; p < NP; ++p) probs[(size_t)row * NP + p] = v[p] * inv;
    }
}

// A[b, p*K + i] = bf16(probs[b,p] * in[b,i])    (8 elems / thread, 16B stores; blockDim 128)
template <typename T>
__global__ void build_a_k(const T* __restrict__ in, const float* __restrict__ probs,
                          __hip_bfloat16* __restrict__ A, int K) {
    int b = blockIdx.y;
    int i = (blockIdx.x * 128 + threadIdx.x) * 8;
    float pv[NP];
#pragma unroll
    for (int p = 0; p < NP; ++p) pv[p] = probs[(size_t)b * NP + p];
    float xv[8];
    if constexpr (sizeof(T) == 2) {
        uint4 u = *(const uint4*)((const unsigned short*)in + (size_t)b * K + i);
        xv[0] = bfbits_to_f(u.x & 0xffff); xv[1] = bfbits_to_f(u.x >> 16);
        xv[2] = bfbits_to_f(u.y & 0xffff); xv[3] = bfbits_to_f(u.y >> 16);
        xv[4] = bfbits_to_f(u.z & 0xffff); xv[5] = bfbits_to_f(u.z >> 16);
        xv[6] = bfbits_to_f(u.w & 0xffff); xv[7] = bfbits_to_f(u.w >> 16);
    } else {
        const float* xp = (const float*)in + (size_t)b * K + i;
        float4 f0 = *(const float4*)xp;
        float4 f1 = *(const float4*)(xp + 4);
        xv[0] = f0.x; xv[1] = f0.y; xv[2] = f0.z; xv[3] = f0.w;
        xv[4] = f1.x; xv[5] = f1.y; xv[6] = f1.z; xv[7] = f1.w;
    }
    size_t base = (size_t)b * ((size_t)NP * K);
#pragma unroll
    for (int p = 0; p < NP; ++p) {
        __hip_bfloat16 tmp[8];
#pragma unroll
        for (int j = 0; j < 8; ++j) tmp[j] = __float2bfloat16(pv[p] * xv[j]);
        uint4 u4;
        __builtin_memcpy(&u4, tmp, 16);
        *(uint4*)(A + base + (size_t)p * K + i) = u4;
    }
}

// ---------------------------------------------------------------------------
// DRN layer GEMM, 256x256 tile, 8-wave (2Mx4N), BK=64, 8-phase counted-vmcnt
// schedule (T3+T4), setprio around MFMA (T5), XOR chunk-swizzled LDS (T2),
// XCD-aware block swizzle (T1).
//   C = relu(A @ Wt^T + Σ_p probs·bexp[p,:]), bf16 out.
//   A [M][K] bf16 (probs pre-folded), Wt [N][K] bf16.  K % 128 == 0.
// LDS map (128 KiB): A: [dbuf][256 rows][8 chunks of 16B]  at 0      (2x32 KB)
//                    B: same                               at 65536  (2x32 KB)
// Stage: thread t, load j -> linear LDS (j*512+t)*16 within half; slot chunk
//        c holds GLOBAL chunk c ^ (row&7)  (gload_lds dest must be linear, so
//        the swizzle is applied on the per-lane global address; reads apply
//        the same XOR).
// Staging schedule (derived safety rule: a gload issued in phase p only
// overwrites a half whose old data was last ds_read in phase <= p-1; the
// barrier pair per phase is the protection):
//   p1: (T+1).A0   p2: (T+1).A1   p3: (T+2).B0   p4: (T+2).B1  + vmcnt(4)
//   p5: (T+2).A0   p6: (T+2).A1   p7: (T+3).B0   p8: (T+3).B1  + vmcnt(4)
// vmcnt(4) at p4 confirms tile T+1 fully landed (2 halves = 4 loads remain in
// flight); at p8 confirms tile T+2. Last iteration stages clamp the SOURCE
// index to NT-1 (dest regions are dead by then) so counts stay uniform.
// ---------------------------------------------------------------------------
__global__ __launch_bounds__(512, 2)
void drn_gemm8_k(const __hip_bfloat16* __restrict__ A, const __hip_bfloat16* __restrict__ Wt,
                 int N, int K, const float* __restrict__ probs,
                 const float* __restrict__ bexp, __hip_bfloat16* __restrict__ C) {
    __shared__ alignas(16) char smem[131072];

    const int tid  = threadIdx.x;
    const int wid  = tid >> 6, lane = tid & 63;
    const int quad = lane >> 4, l16 = lane & 15;
    const int wr = wid >> 2, wc = wid & 3;          // 2 x 4 wave grid

    // XCD-aware swizzle: 8 XCDs get contiguous chunks, n-fastest within.
    const int g   = blockIdx.x;
    const int cpx = gridDim.x >> 3;
    const int wg  = (g & 7) * cpx + (g >> 3);
    const int nbn = N >> 8;
    const int mb  = wg / nbn, nb = wg % nbn;
    const int m0  = mb * 256, n0 = nb * 256;

    // ---- staging addressing (global side carries the swizzle)
    const int arow = tid >> 3;                        // 0..63
    const int gsw  = ((tid & 7) ^ (arow & 7)) << 3;   // swizzled 8-elem chunk
    const __hip_bfloat16* Ag = A  + (size_t)(m0 + arow) * K + gsw;
    const __hip_bfloat16* Bg = Wt + (size_t)(n0 + arow) * K + gsw;
    const size_t r64 = (size_t)64 * K;
    char* aDst = smem + wid * 1024;                   // + lane*16 by HW
    char* bDst = smem + 65536 + wid * 1024;

#define STG_A(dbuf, ksrc, h) do {                                              \
    const __hip_bfloat16* s_ = Ag + (size_t)(ksrc) * 64 + (size_t)(2*(h)) * r64; \
    char* d_ = aDst + (dbuf) * 32768 + (h) * 16384;                            \
    async_ld16(s_,       d_);                                                  \
    async_ld16(s_ + r64, d_ + 8192); } while (0)
#define STG_B(dbuf, ksrc, h) do {                                              \
    const __hip_bfloat16* s_ = Bg + (size_t)(ksrc) * 64 + (size_t)(2*(h)) * r64; \
    char* d_ = bDst + (dbuf) * 32768 + (h) * 16384;                            \
    async_ld16(s_,       d_);                                                  \
    async_ld16(s_ + r64, d_ + 8192); } while (0)

    // ---- ds_read addressing (read applies the same chunk XOR; k=1 flips bit 6)
    const int csw  = (quad ^ (l16 & 7)) << 4;
    const int aoff = (wr * 128 + l16) * 128 + csw;
    const int boff = 65536 + (wc * 64 + l16) * 128 + csw;

#define LDA(dst, dbuf, m, k) dst = *(const bf16x8*)(smem + (dbuf) * 32768 + ((aoff ^ ((k) << 6)) + (m) * 2048))
#define LDB(dst, dbuf, n, k) dst = *(const bf16x8*)(smem + (dbuf) * 32768 + ((boff ^ ((k) << 6)) + (n) * 2048))

#define LD_A2(dbuf, mq)                               \
    LDA(af[0][0], dbuf, 2*(mq),     0); LDA(af[0][1], dbuf, 2*(mq),     1); \
    LDA(af[1][0], dbuf, 2*(mq) + 1, 0); LDA(af[1][1], dbuf, 2*(mq) + 1, 1)
#define LD_B8(dbuf)                                   \
    LDB(bfr[0][0], dbuf, 0, 0); LDB(bfr[0][1], dbuf, 0, 1); \
    LDB(bfr[1][0], dbuf, 1, 0); LDB(bfr[1][1], dbuf, 1, 1); \
    LDB(bfr[2][0], dbuf, 2, 0); LDB(bfr[2][1], dbuf, 2, 1); \
    LDB(bfr[3][0], dbuf, 3, 0); LDB(bfr[3][1], dbuf, 3, 1)

#define PH_SYNC()                                          \
    __builtin_amdgcn_s_barrier();                          \
    asm volatile("s_waitcnt lgkmcnt(0)" ::: "memory");     \
    __builtin_amdgcn_sched_barrier(0)

#define PH_MFMA(q) do {                                    \
    __builtin_amdgcn_s_setprio(1);                         \
    _Pragma("unroll")                                      \
    for (int ml = 0; ml < 2; ++ml)                         \
      _Pragma("unroll")                                    \
      for (int n_ = 0; n_ < 4; ++n_)                       \
        _Pragma("unroll")                                  \
        for (int k_ = 0; k_ < 2; ++k_)                     \
          acc[2*(q)+ml][n_] = __builtin_amdgcn_mfma_f32_16x16x32_bf16( \
              af[ml][k_], bfr[n_][k_], acc[2*(q)+ml][n_], 0, 0, 0);    \
    __builtin_amdgcn_s_setprio(0); } while (0)

#define PH_END()                                           \
    __builtin_amdgcn_s_barrier();                          \
    __builtin_amdgcn_sched_barrier(0)

#define PH_END_VM()                                        \
    asm volatile("s_waitcnt vmcnt(4)" ::: "memory");       \
    __builtin_amdgcn_s_barrier();                          \
    __builtin_amdgcn_sched_barrier(0)

    f32x4 zero = {0.f, 0.f, 0.f, 0.f};
    f32x4 acc[8][4];
#pragma unroll
    for (int m = 0; m < 8; ++m)
#pragma unroll
        for (int n = 0; n < 4; ++n) acc[m][n] = zero;

    const int NT = K >> 6;     // BK=64 tiles (even for all call sites)
    const int NI = NT >> 1;

    // prologue: tile0 complete, tile1 B halves
    STG_A(0, 0, 0); STG_A(0, 0, 1);
    STG_B(0, 0, 0); STG_B(0, 0, 1);
    STG_B(1, 1, 0); STG_B(1, 1, 1);
    asm volatile("s_waitcnt vmcnt(4)" ::: "memory");
    __builtin_amdgcn_s_barrier();
    __builtin_amdgcn_sched_barrier(0);

    bf16x8 af[2][2], bfr[4][2];

    for (int i = 0; i < NI; ++i) {
        const int T  = 2 * i;
        const int k2 = (T + 2 < NT) ? T + 2 : NT - 1;   // clamped source (dest dead on last iter)
        const int k3 = (T + 3 < NT) ? T + 3 : NT - 1;

        // ---- tile T (buf0) ----
        LD_B8(0); LD_A2(0, 0);
        STG_A(1, T + 1, 0);
        PH_SYNC(); PH_MFMA(0); PH_END();

        LD_A2(0, 1);
        STG_A(1, T + 1, 1);
        PH_SYNC(); PH_MFMA(1); PH_END();

        LD_A2(0, 2);
        STG_B(0, k2, 0);
        PH_SYNC(); PH_MFMA(2); PH_END();

        LD_A2(0, 3);
        STG_B(0, k2, 1);
        PH_SYNC(); PH_MFMA(3); PH_END_VM();   // tile T+1 confirmed

        // ---- tile T+1 (buf1) ----
        LD_B8(1); LD_A2(1, 0);
        STG_A(0, k2, 0);
        PH_SYNC(); PH_MFMA(0); PH_END();

        LD_A2(1, 1);
        STG_A(0, k2, 1);
        PH_SYNC(); PH_MFMA(1); PH_END();

        LD_A2(1, 2);
        STG_B(1, k3, 0);
        PH_SYNC(); PH_MFMA(2); PH_END();

        LD_A2(1, 3);
        STG_B(1, k3, 1);
        PH_SYNC(); PH_MFMA(3); PH_END_VM();   // tile T+2 confirmed
    }

    asm volatile("s_waitcnt vmcnt(0)" ::: "memory");  // drain trailing (dead) stages

    // epilogue: + Σ_p probs·bexp[p,:], ReLU, bf16 store
    const int colb = n0 + wc * 64 + l16;
    float bx[4][NP];
#pragma unroll
    for (int n = 0; n < 4; ++n)
#pragma unroll
        for (int p = 0; p < NP; ++p)
            bx[n][p] = bexp[(size_t)p * N + colb + n * 16];
#pragma unroll
    for (int m = 0; m < 8; ++m) {
#pragma unroll
        for (int r = 0; r < 4; ++r) {
            const int row = m0 + wr * 128 + m * 16 + quad * 4 + r;
            const float* pr = probs + (size_t)row * NP;
            f32x4 p0 = *(const f32x4*)pr;
            f32x4 p1 = *(const f32x4*)(pr + 4);
            float pv[NP] = {p0[0], p0[1], p0[2], p0[3], p1[0], p1[1], p1[2], p1[3]};
#pragma unroll
            for (int n = 0; n < 4; ++n) {
                float bsum = 0.f;
#pragma unroll
                for (int p = 0; p < NP; ++p) bsum += pv[p] * bx[n][p];
                float v = fmaxf(acc[m][n][r] + bsum, 0.f);
                C[(size_t)row * N + colb + n * 16] = __float2bfloat16(v);
            }
        }
    }
#undef STG_A
#undef STG_B
#undef LDA
#undef LDB
#undef LD_A2
#undef LD_B8
#undef PH_SYNC
#undef PH_MFMA
#undef PH_END
#undef PH_END_VM
}

// Plain C = A @ Bt^T + bias (f32 out) for the classifier. 128x128, dbuf, swizzled.
__global__ __launch_bounds__(256)
void gemm_bt_k(const __hip_bfloat16* __restrict__ A, const __hip_bfloat16* __restrict__ Bt,
               int M, int N, int K, const float* __restrict__ bias, float* __restrict__ C) {
    __shared__ alignas(16) __hip_bfloat16 As[2 * 128 * 32];
    __shared__ alignas(16) __hip_bfloat16 Bs[2 * 128 * 32];
    const int tid  = threadIdx.x;
    const int wid  = tid >> 6, lane = tid & 63;
    const int quad = lane >> 4, l16 = lane & 15;
    const int waveM = (wid >> 1) << 6, waveN = (wid & 1) << 6;
    const int m0 = blockIdx.x * 128, n0 = blockIdx.y * 128;

    f32x4 zero = {0.f, 0.f, 0.f, 0.f};
    f32x4 acc[4][4];
#pragma unroll
    for (int a = 0; a < 4; ++a)
#pragma unroll
        for (int b = 0; b < 4; ++b) acc[a][b] = zero;

    const int srow = tid >> 2;
    const int skc  = (((tid & 3) ^ (srow & 3) ^ ((srow >> 2) & 3)) << 3);
    const __hip_bfloat16* Ag = A  + (size_t)(m0 + srow) * K + skc;
    const __hip_bfloat16* Bg = Bt + (size_t)(n0 + srow) * K + skc;
    const size_t rowStep = (size_t)64 * K;
    __hip_bfloat16* AsB = As + wid * 512;
    __hip_bfloat16* BsB = Bs + wid * 512;
    const int csel = (quad ^ (l16 & 3) ^ ((l16 >> 2) & 3)) << 3;

    async_ld16(Ag,           AsB);
    async_ld16(Ag + rowStep, AsB + 2048);
    async_ld16(Bg,           BsB);
    async_ld16(Bg + rowStep, BsB + 2048);

    for (int kt = 0; kt < K; kt += 32) {
        const int cur = (kt >> 5) & 1;
        __syncthreads();
        if (kt + 32 < K) {
            const int nb = (1 - cur) * 4096;
            async_ld16(Ag + kt + 32,           AsB + nb);
            async_ld16(Ag + kt + 32 + rowStep, AsB + nb + 2048);
            async_ld16(Bg + kt + 32,           BsB + nb);
            async_ld16(Bg + kt + 32 + rowStep, BsB + nb + 2048);
        }
        const __hip_bfloat16* AsC = As + cur * 4096;
        const __hip_bfloat16* BsC = Bs + cur * 4096;
        bf16x8 af[4], bfr[4];
#pragma unroll
        for (int q = 0; q < 4; ++q) {
            af[q]  = *(const bf16x8*)(AsC + (waveM + q * 16 + l16) * 32 + csel);
            bfr[q] = *(const bf16x8*)(BsC + (waveN + q * 16 + l16) * 32 + csel);
        }
#pragma unroll
        for (int tm = 0; tm < 4; ++tm)
#pragma unroll
            for (int tn = 0; tn < 4; ++tn)
                acc[tm][tn] = __builtin_amdgcn_mfma_f32_16x16x32_bf16(
                    af[tm], bfr[tn], acc[tm][tn], 0, 0, 0);
    }

    const int colb = n0 + waveN + l16;
#pragma unroll
    for (int tm = 0; tm < 4; ++tm)
#pragma unroll
        for (int r = 0; r < 4; ++r) {
            int row = m0 + waveM + tm * 16 + quad * 4 + r;
#pragma unroll
            for (int tn = 0; tn < 4; ++tn)
                C[(size_t)row * N + colb + tn * 16] =
                    acc[tm][tn][r] + bias[colb + tn * 16];
        }
}

extern "C" void kernel_launch(void* const* d_in, const int* in_sizes, int n_in,
                              void* d_out, int out_size, void* d_ws, size_t ws_size,
                              hipStream_t stream) {
    const float* x   = (const float*)d_in[0];
    const float* W1  = (const float*)d_in[1];
    const float* b1  = (const float*)d_in[2];
    const float* S1  = (const float*)d_in[3];
    const float* sb1 = (const float*)d_in[4];
    const float* W2  = (const float*)d_in[5];
    const float* b2  = (const float*)d_in[6];
    const float* S2  = (const float*)d_in[7];
    const float* sb2 = (const float*)d_in[8];
    const float* Wc  = (const float*)d_in[9];
    const float* bc  = (const float*)d_in[10];
    float* out = (float*)d_out;

    char* ws = (char*)d_ws;
    size_t off = 0;
    auto alloc = [&](size_t bytes) {
        char* p = ws + off;
        off += (bytes + 255) & ~(size_t)255;
        return p;
    };
    __hip_bfloat16* W1t = (__hip_bfloat16*)alloc((size_t)H1_SZ * (NP * IN_SZ) * 2);  // 32 MB
    __hip_bfloat16* W2t = (__hip_bfloat16*)alloc((size_t)H2_SZ * (NP * H1_SZ) * 2);  // 64 MB
    __hip_bfloat16* Wct = (__hip_bfloat16*)alloc((size_t)OUT_SZ * H2_SZ * 2);        //  4 MB
    float* probs1       = (float*)alloc((size_t)B_SZ * NP * 4);
    float* probs2       = (float*)alloc((size_t)B_SZ * NP * 4);
    __hip_bfloat16* h1  = (__hip_bfloat16*)alloc((size_t)B_SZ * H1_SZ * 2);          // 32 MB
    __hip_bfloat16* h2  = (__hip_bfloat16*)alloc((size_t)B_SZ * H2_SZ * 2);          // 32 MB
    __hip_bfloat16* Abuf= (__hip_bfloat16*)alloc((size_t)B_SZ * (NP * H1_SZ) * 2);   // 256 MB (shared)

    dim3 tb(32, 8);
    transpose_cast_k<<<dim3(H1_SZ / 32, (NP * IN_SZ) / 32), tb, 0, stream>>>(W1, W1t, NP * IN_SZ, H1_SZ);
    transpose_cast_k<<<dim3(H2_SZ / 32, (NP * H1_SZ) / 32), tb, 0, stream>>>(W2, W2t, NP * H1_SZ, H2_SZ);
    transpose_cast_k<<<dim3(OUT_SZ / 32, H2_SZ / 32), tb, 0, stream>>>(Wc, Wct, H2_SZ, OUT_SZ);

    // layer 1
    selector_k<float><<<B_SZ / 4, dim3(64, 4), 0, stream>>>(x, S1, sb1, probs1, IN_SZ);
    build_a_k<float><<<dim3(IN_SZ / 1024, B_SZ), 128, 0, stream>>>(x, probs1, Abuf, IN_SZ);
    drn_gemm8_k<<<(B_SZ / 256) * (H1_SZ / 256), 512, 0, stream>>>(
        Abuf, W1t, H1_SZ, NP * IN_SZ, probs1, b1, h1);

    // layer 2
    selector_k<__hip_bfloat16><<<B_SZ / 4, dim3(64, 4), 0, stream>>>(h1, S2, sb2, probs2, H1_SZ);
    build_a_k<__hip_bfloat16><<<dim3(H1_SZ / 1024, B_SZ), 128, 0, stream>>>(h1, probs2, Abuf, H1_SZ);
    drn_gemm8_k<<<(B_SZ / 256) * (H2_SZ / 256), 512, 0, stream>>>(
        Abuf, W2t, H2_SZ, NP * H1_SZ, probs2, b2, h2);

    // classifier
    gemm_bt_k<<<dim3(B_SZ / 128, OUT_SZ / 128), 256, 0, stream>>>(
        h2, Wct, B_SZ, OUT_SZ, H2_SZ, bc, out);
}

// Round 2
// 1036.336 us; speedup vs baseline: 1.3962x; 1.0056x over previous
//
#include <hip/hip_runtime.h>
#include <hip/hip_bf16.h>

// Problem dims
#define B_SZ   8192
#define IN_SZ  1024
#define H1_SZ  2048
#define H2_SZ  2048
#define OUT_SZ 1024
#define NP     8

typedef __bf16 bf16x8 __attribute__((ext_vector_type(8)));
typedef float  f32x4  __attribute__((ext_vector_type(4)));

__device__ __forceinline__ void async_ld16(const void* g, void* l) {
    __builtin_amdgcn_global_load_lds(
        (const __attribute__((address_space(1))) unsigned int*)g,
        (__attribute__((address_space(3))) unsigned int*)l,
        16, 0, 0);
}

// plain f32 -> bf16 cast, 8 elems/thread
__global__ void cast_bf16_k(const float* __restrict__ in, __hip_bfloat16* __restrict__ out) {
    size_t i = ((size_t)blockIdx.x * 256 + threadIdx.x) * 8;
    float4 f0 = *(const float4*)(in + i);
    float4 f1 = *(const float4*)(in + i + 4);
    __hip_bfloat16 t[8] = {
        __float2bfloat16(f0.x), __float2bfloat16(f0.y),
        __float2bfloat16(f0.z), __float2bfloat16(f0.w),
        __float2bfloat16(f1.x), __float2bfloat16(f1.y),
        __float2bfloat16(f1.z), __float2bfloat16(f1.w)};
    uint4 u4;
    __builtin_memcpy(&u4, t, 16);
    *(uint4*)(out + i) = u4;
}

// in [K][N] f32  ->  out [N][K] bf16  (transposed cast; 4B packed stores)
__global__ void transpose_cast_k(const float* __restrict__ in, __hip_bfloat16* __restrict__ out,
                                 int K, int N) {
    __shared__ float tile[32][33];
    int n0 = blockIdx.x * 32, k0 = blockIdx.y * 32;
    int tx = threadIdx.x, ty = threadIdx.y;  // 32 x 8
#pragma unroll
    for (int j = 0; j < 4; ++j)
        tile[ty + j * 8][tx] = in[(size_t)(k0 + ty + j * 8) * N + (n0 + tx)];
    __syncthreads();
    const int kk = (tx & 15) * 2;
#pragma unroll
    for (int j = 0; j < 2; ++j) {
        int nn = ty + j * 8 + (tx >> 4) * 16;
        __hip_bfloat16 t2[2] = {__float2bfloat16(tile[kk][nn]),
                                __float2bfloat16(tile[kk + 1][nn])};
        unsigned int u;
        __builtin_memcpy(&u, t2, 4);
        *(unsigned int*)(out + (size_t)(n0 + nn) * K + (k0 + kk)) = u;
    }
}

// probs[b,:] = softmax(in[b,:] @ S + sb)   — one wave per row.
// Also writes ratT[p][b]: running-rescale factors for the fused GEMM:
//   ratT[p<7] = v[p]/v[p+1]  (unnormalized numerators; normalization cancels)
//   ratT[7]   = probs[b,7]   (final normalize-and-scale)
template <typename T>
__global__ void selector_k(const T* __restrict__ in, const float* __restrict__ S,
                           const float* __restrict__ sb, float* __restrict__ probs,
                           float* __restrict__ ratT, int K) {
    int row  = blockIdx.x * blockDim.y + threadIdx.y;
    int lane = threadIdx.x;
    float acc[NP];
#pragma unroll
    for (int p = 0; p < NP; ++p) acc[p] = 0.f;
    const T* xr = in + (size_t)row * K;
    for (int k = lane; k < K; k += 64) {
        float xv;
        if constexpr (sizeof(T) == 2) xv = __bfloat162float(xr[k]);
        else                          xv = (float)xr[k];
        const float* sr = S + (size_t)k * NP;
#pragma unroll
        for (int p = 0; p < NP; ++p) acc[p] += xv * sr[p];
    }
#pragma unroll
    for (int p = 0; p < NP; ++p)
#pragma unroll
        for (int off = 32; off > 0; off >>= 1)
            acc[p] += __shfl_down(acc[p], off, 64);
    if (lane == 0) {
        float v[NP], m = -1e30f;
#pragma unroll
        for (int p = 0; p < NP; ++p) { v[p] = acc[p] + sb[p]; m = fmaxf(m, v[p]); }
        float s = 0.f;
#pragma unroll
        for (int p = 0; p < NP; ++p) { v[p] = expf(v[p] - m); s += v[p]; }
        float inv = 1.f / s;
#pragma unroll
        for (int p = 0; p < NP; ++p) probs[(size_t)row * NP + p] = v[p] * inv;
#pragma unroll
        for (int p = 0; p < NP - 1; ++p) ratT[(size_t)p * B_SZ + row] = v[p] / v[p + 1];
        ratT[(size_t)(NP - 1) * B_SZ + row] = v[NP - 1] * inv;
    }
}

// ---------------------------------------------------------------------------
// FUSED DRN layer GEMM: C = relu(Σ_p probs[b,p]·(x @ W[p]) + Σ_p probs·bexp[p,:])
// A-operand is the RAW activation x [M][Kin] bf16 (no probs-folded copy).
// The probs weighting is applied via a single-accumulator running rescale:
// after finishing K-segment p, acc *= ratT[p][row]  (= v[p]/v[p+1], final
// segment = pv[7]), which telescopes to acc = Σ_p pv[p]·G_p. Segment
// boundaries land on even tile counts (TPS = Kin/64 tiles per segment), so
// the fold sits at the bottom of the 2-tile iteration. Fold scales are a
// per-lane f32x4 load (C/D rows = quad*4+reg) from ratT[p][row].
// B-operand Wt [N][K=NP*Kin] iterates the full K; A re-reads x per segment
// (k mod Kin), L2/L3-resident.
// Schedule: 256x256 tile, 8-wave, BK=64, 8-phase counted-vmcnt (see R1).
// ---------------------------------------------------------------------------
template <int TPS>
__global__ __launch_bounds__(512, 2)
void drn_gemm8_k(const __hip_bfloat16* __restrict__ A, const __hip_bfloat16* __restrict__ Wt,
                 int N, int K, int Kin, const float* __restrict__ ratT,
                 const float* __restrict__ probs, const float* __restrict__ bexp,
                 __hip_bfloat16* __restrict__ C) {
    __shared__ alignas(16) char smem[131072];

    const int tid  = threadIdx.x;
    const int wid  = tid >> 6, lane = tid & 63;
    const int quad = lane >> 4, l16 = lane & 15;
    const int wr = wid >> 2, wc = wid & 3;          // 2 x 4 wave grid

    // XCD-aware swizzle: 8 XCDs get contiguous chunks, n-fastest within.
    const int g   = blockIdx.x;
    const int cpx = gridDim.x >> 3;
    const int wg  = (g & 7) * cpx + (g >> 3);
    const int nbn = N >> 8;
    const int mb  = wg / nbn, nb = wg % nbn;
    const int m0  = mb * 256, n0 = nb * 256;

    // ---- staging addressing (global side carries the chunk swizzle)
    const int arow = tid >> 3;                        // 0..63
    const int gsw  = ((tid & 7) ^ (arow & 7)) << 3;   // swizzled 8-elem chunk
    const __hip_bfloat16* Ag = A  + (size_t)(m0 + arow) * Kin + gsw;
    const __hip_bfloat16* Bg = Wt + (size_t)(n0 + arow) * K + gsw;
    const size_t r64a = (size_t)64 * Kin;
    const size_t r64b = (size_t)64 * K;
    char* aDst = smem + wid * 1024;                   // + lane*16 by HW
    char* bDst = smem + 65536 + wid * 1024;

#define STG_A(dbuf, ksrc, h) do {                                              \
    const __hip_bfloat16* s_ = Ag + (((ksrc) & (TPS - 1)) * 64) + (size_t)(2*(h)) * r64a; \
    char* d_ = aDst + (dbuf) * 32768 + (h) * 16384;                            \
    async_ld16(s_,        d_);                                                 \
    async_ld16(s_ + r64a, d_ + 8192); } while (0)
#define STG_B(dbuf, ksrc, h) do {                                              \
    const __hip_bfloat16* s_ = Bg + ((size_t)(ksrc) * 64) + (size_t)(2*(h)) * r64b; \
    char* d_ = bDst + (dbuf) * 32768 + (h) * 16384;                            \
    async_ld16(s_,        d_);                                                 \
    async_ld16(s_ + r64b, d_ + 8192); } while (0)

    // ---- ds_read addressing (read applies the same chunk XOR; k=1 flips bit 6)
    const int csw  = (quad ^ (l16 & 7)) << 4;
    const int aoff = (wr * 128 + l16) * 128 + csw;
    const int boff = 65536 + (wc * 64 + l16) * 128 + csw;

#define LDA(dst, dbuf, m, k) dst = *(const bf16x8*)(smem + (dbuf) * 32768 + ((aoff ^ ((k) << 6)) + (m) * 2048))
#define LDB(dst, dbuf, n, k) dst = *(const bf16x8*)(smem + (dbuf) * 32768 + ((boff ^ ((k) << 6)) + (n) * 2048))

#define LD_A2(dbuf, mq)                               \
    LDA(af[0][0], dbuf, 2*(mq),     0); LDA(af[0][1], dbuf, 2*(mq),     1); \
    LDA(af[1][0], dbuf, 2*(mq) + 1, 0); LDA(af[1][1], dbuf, 2*(mq) + 1, 1)
#define LD_B8(dbuf)                                   \
    LDB(bfr[0][0], dbuf, 0, 0); LDB(bfr[0][1], dbuf, 0, 1); \
    LDB(bfr[1][0], dbuf, 1, 0); LDB(bfr[1][1], dbuf, 1, 1); \
    LDB(bfr[2][0], dbuf, 2, 0); LDB(bfr[2][1], dbuf, 2, 1); \
    LDB(bfr[3][0], dbuf, 3, 0); LDB(bfr[3][1], dbuf, 3, 1)

#define PH_SYNC()                                          \
    __builtin_amdgcn_s_barrier();                          \
    asm volatile("s_waitcnt lgkmcnt(0)" ::: "memory");     \
    __builtin_amdgcn_sched_barrier(0)

#define PH_MFMA(q) do {                                    \
    __builtin_amdgcn_s_setprio(1);                         \
    _Pragma("unroll")                                      \
    for (int ml = 0; ml < 2; ++ml)                         \
      _Pragma("unroll")                                    \
      for (int n_ = 0; n_ < 4; ++n_)                       \
        _Pragma("unroll")                                  \
        for (int k_ = 0; k_ < 2; ++k_)                     \
          acc[2*(q)+ml][n_] = __builtin_amdgcn_mfma_f32_16x16x32_bf16( \
              af[ml][k_], bfr[n_][k_], acc[2*(q)+ml][n_], 0, 0, 0);    \
    __builtin_amdgcn_s_setprio(0); } while (0)

#define PH_END()                                           \
    __builtin_amdgcn_s_barrier();                          \
    __builtin_amdgcn_sched_barrier(0)

#define PH_END_VM()                                        \
    asm volatile("s_waitcnt vmcnt(4)" ::: "memory");       \
    __builtin_amdgcn_s_barrier();                          \
    __builtin_amdgcn_sched_barrier(0)

    f32x4 zero = {0.f, 0.f, 0.f, 0.f};
    f32x4 acc[8][4];
#pragma unroll
    for (int m = 0; m < 8; ++m)
#pragma unroll
        for (int n = 0; n < 4; ++n) acc[m][n] = zero;

    const int NT = K >> 6;     // BK=64 tiles (even for all call sites)
    const int NI = NT >> 1;

    // prologue: tile0 complete, tile1 B halves
    STG_A(0, 0, 0); STG_A(0, 0, 1);
    STG_B(0, 0, 0); STG_B(0, 0, 1);
    STG_B(1, 1, 0); STG_B(1, 1, 1);
    asm volatile("s_waitcnt vmcnt(4)" ::: "memory");
    __builtin_amdgcn_s_barrier();
    __builtin_amdgcn_sched_barrier(0);

    bf16x8 af[2][2], bfr[4][2];

    for (int i = 0; i < NI; ++i) {
        const int T  = 2 * i;
        const int k2 = (T + 2 < NT) ? T + 2 : NT - 1;   // clamped source (dest dead on last iter)
        const int k3 = (T + 3 < NT) ? T + 3 : NT - 1;

        // ---- tile T (buf0) ----
        LD_B8(0); LD_A2(0, 0);
        STG_A(1, T + 1, 0);
        PH_SYNC(); PH_MFMA(0); PH_END();

        LD_A2(0, 1);
        STG_A(1, T + 1, 1);
        PH_SYNC(); PH_MFMA(1); PH_END();

        LD_A2(0, 2);
        STG_B(0, k2, 0);
        PH_SYNC(); PH_MFMA(2); PH_END();

        LD_A2(0, 3);
        STG_B(0, k2, 1);
        PH_SYNC(); PH_MFMA(3); PH_END_VM();   // tile T+1 confirmed

        // ---- tile T+1 (buf1) ----
        LD_B8(1); LD_A2(1, 0);
        STG_A(0, k2, 0);
        PH_SYNC(); PH_MFMA(0); PH_END();

        LD_A2(1, 1);
        STG_A(0, k2, 1);
        PH_SYNC(); PH_MFMA(1); PH_END();

        LD_A2(1, 2);
        STG_B(1, k3, 0);
        PH_SYNC(); PH_MFMA(2); PH_END();

        LD_A2(1, 3);
        STG_B(1, k3, 1);
        PH_SYNC(); PH_MFMA(3); PH_END_VM();   // tile T+2 confirmed

        // ---- segment-boundary fold: acc *= ratT[p][row] (telescoping probs) ----
        if (((i + 1) & (TPS / 2 - 1)) == 0) {
            const int p = (i + 1) / (TPS / 2) - 1;     // 0..7
            const float* rp = ratT + (size_t)p * B_SZ + (m0 + wr * 128 + quad * 4);
            f32x4 rr[8];
#pragma unroll
            for (int m = 0; m < 8; ++m) rr[m] = *(const f32x4*)(rp + m * 16);
#pragma unroll
            for (int m = 0; m < 8; ++m)
#pragma unroll
                for (int n = 0; n < 4; ++n)
                    acc[m][n] *= rr[m];
        }
    }

    asm volatile("s_waitcnt vmcnt(0)" ::: "memory");  // drain trailing (dead) stages

    // epilogue: + Σ_p probs·bexp[p,:], ReLU, bf16 store
    const int colb = n0 + wc * 64 + l16;
    float bx[4][NP];
#pragma unroll
    for (int n = 0; n < 4; ++n)
#pragma unroll
        for (int p = 0; p < NP; ++p)
            bx[n][p] = bexp[(size_t)p * N + colb + n * 16];
#pragma unroll
    for (int m = 0; m < 8; ++m) {
#pragma unroll
        for (int r = 0; r < 4; ++r) {
            const int row = m0 + wr * 128 + m * 16 + quad * 4 + r;
            const float* pr = probs + (size_t)row * NP;
            f32x4 p0 = *(const f32x4*)pr;
            f32x4 p1 = *(const f32x4*)(pr + 4);
            float pv[NP] = {p0[0], p0[1], p0[2], p0[3], p1[0], p1[1], p1[2], p1[3]};
#pragma unroll
            for (int n = 0; n < 4; ++n) {
                float bsum = 0.f;
#pragma unroll
                for (int p = 0; p < NP; ++p) bsum += pv[p] * bx[n][p];
                float v = fmaxf(acc[m][n][r] + bsum, 0.f);
                C[(size_t)row * N + colb + n * 16] = __float2bfloat16(v);
            }
        }
    }
#undef STG_A
#undef STG_B
#undef LDA
#undef LDB
#undef LD_A2
#undef LD_B8
#undef PH_SYNC
#undef PH_MFMA
#undef PH_END
#undef PH_END_VM
}

// Plain C = A @ Bt^T + bias (f32 out) for the classifier. 128x128, dbuf, swizzled.
__global__ __launch_bounds__(256)
void gemm_bt_k(const __hip_bfloat16* __restrict__ A, const __hip_bfloat16* __restrict__ Bt,
               int M, int N, int K, const float* __restrict__ bias, float* __restrict__ C) {
    __shared__ alignas(16) __hip_bfloat16 As[2 * 128 * 32];
    __shared__ alignas(16) __hip_bfloat16 Bs[2 * 128 * 32];
    const int tid  = threadIdx.x;
    const int wid  = tid >> 6, lane = tid & 63;
    const int quad = lane >> 4, l16 = lane & 15;
    const int waveM = (wid >> 1) << 6, waveN = (wid & 1) << 6;
    const int m0 = blockIdx.x * 128, n0 = blockIdx.y * 128;

    f32x4 zero = {0.f, 0.f, 0.f, 0.f};
    f32x4 acc[4][4];
#pragma unroll
    for (int a = 0; a < 4; ++a)
#pragma unroll
        for (int b = 0; b < 4; ++b) acc[a][b] = zero;

    const int srow = tid >> 2;
    const int skc  = (((tid & 3) ^ (srow & 3) ^ ((srow >> 2) & 3)) << 3);
    const __hip_bfloat16* Ag = A  + (size_t)(m0 + srow) * K + skc;
    const __hip_bfloat16* Bg = Bt + (size_t)(n0 + srow) * K + skc;
    const size_t rowStep = (size_t)64 * K;
    __hip_bfloat16* AsB = As + wid * 512;
    __hip_bfloat16* BsB = Bs + wid * 512;
    const int csel = (quad ^ (l16 & 3) ^ ((l16 >> 2) & 3)) << 3;

    async_ld16(Ag,           AsB);
    async_ld16(Ag + rowStep, AsB + 2048);
    async_ld16(Bg,           BsB);
    async_ld16(Bg + rowStep, BsB + 2048);

    for (int kt = 0; kt < K; kt += 32) {
        const int cur = (kt >> 5) & 1;
        __syncthreads();
        if (kt + 32 < K) {
            const int nb = (1 - cur) * 4096;
            async_ld16(Ag + kt + 32,           AsB + nb);
            async_ld16(Ag + kt + 32 + rowStep, AsB + nb + 2048);
            async_ld16(Bg + kt + 32,           BsB + nb);
            async_ld16(Bg + kt + 32 + rowStep, BsB + nb + 2048);
        }
        const __hip_bfloat16* AsC = As + cur * 4096;
        const __hip_bfloat16* BsC = Bs + cur * 4096;
        bf16x8 af[4], bfr[4];
#pragma unroll
        for (int q = 0; q < 4; ++q) {
            af[q]  = *(const bf16x8*)(AsC + (waveM + q * 16 + l16) * 32 + csel);
            bfr[q] = *(const bf16x8*)(BsC + (waveN + q * 16 + l16) * 32 + csel);
        }
#pragma unroll
        for (int tm = 0; tm < 4; ++tm)
#pragma unroll
            for (int tn = 0; tn < 4; ++tn)
                acc[tm][tn] = __builtin_amdgcn_mfma_f32_16x16x32_bf16(
                    af[tm], bfr[tn], acc[tm][tn], 0, 0, 0);
    }

    const int colb = n0 + waveN + l16;
#pragma unroll
    for (int tm = 0; tm < 4; ++tm)
#pragma unroll
        for (int r = 0; r < 4; ++r) {
            int row = m0 + waveM + tm * 16 + quad * 4 + r;
#pragma unroll
            for (int tn = 0; tn < 4; ++tn)
                C[(size_t)row * N + colb + tn * 16] =
                    acc[tm][tn][r] + bias[colb + tn * 16];
        }
}

extern "C" void kernel_launch(void* const* d_in, const int* in_sizes, int n_in,
                              void* d_out, int out_size, void* d_ws, size_t ws_size,
                              hipStream_t stream) {
    const float* x   = (const float*)d_in[0];
    const float* W1  = (const float*)d_in[1];
    const float* b1  = (const float*)d_in[2];
    const float* S1  = (const float*)d_in[3];
    const float* sb1 = (const float*)d_in[4];
    const float* W2  = (const float*)d_in[5];
    const float* b2  = (const float*)d_in[6];
    const float* S2  = (const float*)d_in[7];
    const float* sb2 = (const float*)d_in[8];
    const float* Wc  = (const float*)d_in[9];
    const float* bc  = (const float*)d_in[10];
    float* out = (float*)d_out;

    char* ws = (char*)d_ws;
    size_t off = 0;
    auto alloc = [&](size_t bytes) {
        char* p = ws + off;
        off += (bytes + 255) & ~(size_t)255;
        return p;
    };
    __hip_bfloat16* W1t = (__hip_bfloat16*)alloc((size_t)H1_SZ * (NP * IN_SZ) * 2);  // 32 MB
    __hip_bfloat16* W2t = (__hip_bfloat16*)alloc((size_t)H2_SZ * (NP * H1_SZ) * 2);  // 64 MB
    __hip_bfloat16* Wct = (__hip_bfloat16*)alloc((size_t)OUT_SZ * H2_SZ * 2);        //  4 MB
    float* probs1       = (float*)alloc((size_t)B_SZ * NP * 4);
    float* probs2       = (float*)alloc((size_t)B_SZ * NP * 4);
    float* rat1         = (float*)alloc((size_t)NP * B_SZ * 4);
    float* rat2         = (float*)alloc((size_t)NP * B_SZ * 4);
    __hip_bfloat16* xbf = (__hip_bfloat16*)alloc((size_t)B_SZ * IN_SZ * 2);          // 16 MB
    __hip_bfloat16* h1  = (__hip_bfloat16*)alloc((size_t)B_SZ * H1_SZ * 2);          // 32 MB
    __hip_bfloat16* h2  = (__hip_bfloat16*)alloc((size_t)B_SZ * H2_SZ * 2);          // 32 MB

    dim3 tb(32, 8);
    transpose_cast_k<<<dim3(H1_SZ / 32, (NP * IN_SZ) / 32), tb, 0, stream>>>(W1, W1t, NP * IN_SZ, H1_SZ);
    transpose_cast_k<<<dim3(H2_SZ / 32, (NP * H1_SZ) / 32), tb, 0, stream>>>(W2, W2t, NP * H1_SZ, H2_SZ);
    transpose_cast_k<<<dim3(OUT_SZ / 32, H2_SZ / 32), tb, 0, stream>>>(Wc, Wct, H2_SZ, OUT_SZ);
    cast_bf16_k<<<(B_SZ * IN_SZ) / (256 * 8), 256, 0, stream>>>(x, xbf);

    // layer 1 (TPS = IN/64 = 16)
    selector_k<float><<<B_SZ / 4, dim3(64, 4), 0, stream>>>(x, S1, sb1, probs1, rat1, IN_SZ);
    drn_gemm8_k<16><<<(B_SZ / 256) * (H1_SZ / 256), 512, 0, stream>>>(
        xbf, W1t, H1_SZ, NP * IN_SZ, IN_SZ, rat1, probs1, b1, h1);

    // layer 2 (TPS = H1/64 = 32)
    selector_k<__hip_bfloat16><<<B_SZ / 4, dim3(64, 4), 0, stream>>>(h1, S2, sb2, probs2, rat2, H1_SZ);
    drn_gemm8_k<32><<<(B_SZ / 256) * (H2_SZ / 256), 512, 0, stream>>>(
        h1, W2t, H2_SZ, NP * H1_SZ, H1_SZ, rat2, probs2, b2, h2);

    // classifier
    gemm_bt_k<<<dim3(B_SZ / 128, OUT_SZ / 128), 256, 0, stream>>>(
        h2, Wct, B_SZ, OUT_SZ, H2_SZ, bc, out);
}

// Round 3
// 990.769 us; speedup vs baseline: 1.4605x; 1.0460x over previous
//
#include <hip/hip_runtime.h>
#include <hip/hip_bf16.h>

// Problem dims
#define B_SZ   8192
#define IN_SZ  1024
#define H1_SZ  2048
#define H2_SZ  2048
#define OUT_SZ 1024
#define NP     8

typedef __bf16 bf16x8 __attribute__((ext_vector_type(8)));
typedef float  f32x4  __attribute__((ext_vector_type(4)));

__device__ __forceinline__ void async_ld16(const void* g, void* l) {
    __builtin_amdgcn_global_load_lds(
        (const __attribute__((address_space(1))) unsigned int*)g,
        (__attribute__((address_space(3))) unsigned int*)l,
        16, 0, 0);
}

// ---------------------------------------------------------------------------
// Unified prep kernel: 3 weight transposes (f32 [K][N] -> bf16 [N][K]) + x cast,
// one dispatch (flat block ranges) instead of 4 launches.
// ---------------------------------------------------------------------------
__device__ __forceinline__ void transpose_body(float (*tile)[33],
                                               const float* __restrict__ in,
                                               __hip_bfloat16* __restrict__ out,
                                               int K, int N, int bx, int by) {
    int n0 = bx * 32, k0 = by * 32;
    int tx = threadIdx.x, ty = threadIdx.y;  // 32 x 8
#pragma unroll
    for (int j = 0; j < 4; ++j)
        tile[ty + j * 8][tx] = in[(size_t)(k0 + ty + j * 8) * N + (n0 + tx)];
    __syncthreads();
    const int kk = (tx & 15) * 2;
#pragma unroll
    for (int j = 0; j < 2; ++j) {
        int nn = ty + j * 8 + (tx >> 4) * 16;
        __hip_bfloat16 t2[2] = {__float2bfloat16(tile[kk][nn]),
                                __float2bfloat16(tile[kk + 1][nn])};
        unsigned int u;
        __builtin_memcpy(&u, t2, 4);
        *(unsigned int*)(out + (size_t)(n0 + nn) * K + (k0 + kk)) = u;
    }
}

__global__ void prep_k(const float* __restrict__ W1, const float* __restrict__ W2,
                       const float* __restrict__ Wc, const float* __restrict__ x,
                       __hip_bfloat16* __restrict__ W1t, __hip_bfloat16* __restrict__ W2t,
                       __hip_bfloat16* __restrict__ Wct, __hip_bfloat16* __restrict__ xbf) {
    __shared__ float tile[32][33];
    int id = blockIdx.x;
    const int nA = (H1_SZ / 32) * ((NP * IN_SZ) / 32);   // 16384
    const int nB = (H2_SZ / 32) * ((NP * H1_SZ) / 32);   // 32768
    const int nC = (OUT_SZ / 32) * (H2_SZ / 32);         // 2048
    if (id < nA) {
        transpose_body(tile, W1, W1t, NP * IN_SZ, H1_SZ, id % (H1_SZ / 32), id / (H1_SZ / 32));
        return;
    }
    id -= nA;
    if (id < nB) {
        transpose_body(tile, W2, W2t, NP * H1_SZ, H2_SZ, id % (H2_SZ / 32), id / (H2_SZ / 32));
        return;
    }
    id -= nB;
    if (id < nC) {
        transpose_body(tile, Wc, Wct, H2_SZ, OUT_SZ, id % (OUT_SZ / 32), id / (OUT_SZ / 32));
        return;
    }
    id -= nC;
    {   // cast x -> bf16, 8 elems/thread
        int t = threadIdx.y * 32 + threadIdx.x;
        size_t i = ((size_t)id * 256 + t) * 8;
        float4 f0 = *(const float4*)(x + i);
        float4 f1 = *(const float4*)(x + i + 4);
        __hip_bfloat16 tt[8] = {
            __float2bfloat16(f0.x), __float2bfloat16(f0.y),
            __float2bfloat16(f0.z), __float2bfloat16(f0.w),
            __float2bfloat16(f1.x), __float2bfloat16(f1.y),
            __float2bfloat16(f1.z), __float2bfloat16(f1.w)};
        uint4 u4;
        __builtin_memcpy(&u4, tt, 16);
        *(uint4*)(xbf + i) = u4;
    }
}

// probs[b,:] = softmax(in[b,:] @ S + sb)   — one wave per row.
// Also writes ratT[p][b]: running-rescale factors for the fused GEMM:
//   ratT[p<7] = v[p]/v[p+1]  (unnormalized numerators; normalization cancels)
//   ratT[7]   = probs[b,7]   (final normalize-and-scale)
template <typename T>
__global__ void selector_k(const T* __restrict__ in, const float* __restrict__ S,
                           const float* __restrict__ sb, float* __restrict__ probs,
                           float* __restrict__ ratT, int K) {
    int row  = blockIdx.x * blockDim.y + threadIdx.y;
    int lane = threadIdx.x;
    float acc[NP];
#pragma unroll
    for (int p = 0; p < NP; ++p) acc[p] = 0.f;
    const T* xr = in + (size_t)row * K;
    for (int k = lane; k < K; k += 64) {
        float xv;
        if constexpr (sizeof(T) == 2) xv = __bfloat162float(xr[k]);
        else                          xv = (float)xr[k];
        const float* sr = S + (size_t)k * NP;
#pragma unroll
        for (int p = 0; p < NP; ++p) acc[p] += xv * sr[p];
    }
#pragma unroll
    for (int p = 0; p < NP; ++p)
#pragma unroll
        for (int off = 32; off > 0; off >>= 1)
            acc[p] += __shfl_down(acc[p], off, 64);
    if (lane == 0) {
        float v[NP], m = -1e30f;
#pragma unroll
        for (int p = 0; p < NP; ++p) { v[p] = acc[p] + sb[p]; m = fmaxf(m, v[p]); }
        float s = 0.f;
#pragma unroll
        for (int p = 0; p < NP; ++p) { v[p] = expf(v[p] - m); s += v[p]; }
        float inv = 1.f / s;
#pragma unroll
        for (int p = 0; p < NP; ++p) probs[(size_t)row * NP + p] = v[p] * inv;
#pragma unroll
        for (int p = 0; p < NP - 1; ++p) ratT[(size_t)p * B_SZ + row] = v[p] / v[p + 1];
        ratT[(size_t)(NP - 1) * B_SZ + row] = v[NP - 1] * inv;
    }
}

// ---------------------------------------------------------------------------
// FUSED DRN layer GEMM: C = relu(Σ_p probs[b,p]·(x @ W[p]) + Σ_p probs·bexp[p,:])
// 256x256 tile, 8 waves (2Mx4N), BK=64, 8-phase schedule with:
//  - counted vmcnt (never 0 in loop): waits vmcnt(4)@ph2, (2)@ph3, (4)@ph6, (2)@ph7
//  - PIPELINED FRAGMENT LOADS: ds_reads for phase p+1 issue during phase p into
//    a second register set (afA/afB, bfrA/bfrB ping-pong); no manual lgkmcnt —
//    compiler emits counted use-waits, so the LDS pipe drains DURING MFMA.
//    Read-region validity: a region is readable the phase AFTER the phase whose
//    {vmcnt + barrier} confirmed it.  Staging: ph1-2 A(T+1)->b1, ph3-4 B(T+2)->b0,
//    ph5-6 A(T+2)->b0, ph7-8 B(T+3)->b1.  Confirms: ph2->B(T+1), ph3->A(T+1),
//    ph6->B(T+2), ph7->A(T+2).  All write-after-read hazards separated by >=1
//    barrier pair from the reads' use-waits (checked region by region).
//  - probs folded via telescoping acc rescale at segment boundaries (ratT).
// ---------------------------------------------------------------------------
template <int TPS>
__global__ __launch_bounds__(512, 2)
void drn_gemm8_k(const __hip_bfloat16* __restrict__ A, const __hip_bfloat16* __restrict__ Wt,
                 int N, int K, int Kin, const float* __restrict__ ratT,
                 const float* __restrict__ probs, const float* __restrict__ bexp,
                 __hip_bfloat16* __restrict__ C) {
    __shared__ alignas(16) char smem[131072];

    const int tid  = threadIdx.x;
    const int wid  = tid >> 6, lane = tid & 63;
    const int quad = lane >> 4, l16 = lane & 15;
    const int wr = wid >> 2, wc = wid & 3;          // 2 x 4 wave grid

    // XCD-aware swizzle: 8 XCDs get contiguous chunks, n-fastest within.
    const int g   = blockIdx.x;
    const int cpx = gridDim.x >> 3;
    const int wg  = (g & 7) * cpx + (g >> 3);
    const int nbn = N >> 8;
    const int mb  = wg / nbn, nb = wg % nbn;
    const int m0  = mb * 256, n0 = nb * 256;

    // ---- staging addressing (global side carries the chunk swizzle)
    const int arow = tid >> 3;                        // 0..63
    const int gsw  = ((tid & 7) ^ (arow & 7)) << 3;   // swizzled 8-elem chunk
    const __hip_bfloat16* Ag = A  + (size_t)(m0 + arow) * Kin + gsw;
    const __hip_bfloat16* Bg = Wt + (size_t)(n0 + arow) * K + gsw;
    const size_t r64a = (size_t)64 * Kin;
    const size_t r64b = (size_t)64 * K;
    char* aDst = smem + wid * 1024;                   // + lane*16 by HW
    char* bDst = smem + 65536 + wid * 1024;

#define STG_A(dbuf, ksrc, h) do {                                              \
    const __hip_bfloat16* s_ = Ag + (((ksrc) & (TPS - 1)) * 64) + (size_t)(2*(h)) * r64a; \
    char* d_ = aDst + (dbuf) * 32768 + (h) * 16384;                            \
    async_ld16(s_,        d_);                                                 \
    async_ld16(s_ + r64a, d_ + 8192); } while (0)
#define STG_B(dbuf, ksrc, h) do {                                              \
    const __hip_bfloat16* s_ = Bg + ((size_t)(ksrc) * 64) + (size_t)(2*(h)) * r64b; \
    char* d_ = bDst + (dbuf) * 32768 + (h) * 16384;                            \
    async_ld16(s_,        d_);                                                 \
    async_ld16(s_ + r64b, d_ + 8192); } while (0)

    // ---- ds_read addressing (read applies the same chunk XOR; k=1 flips bit 6)
    const int csw  = (quad ^ (l16 & 7)) << 4;
    const int aoff = (wr * 128 + l16) * 128 + csw;
    const int boff = 65536 + (wc * 64 + l16) * 128 + csw;

#define LDA(dst, dbuf, m, k) dst = *(const bf16x8*)(smem + (dbuf) * 32768 + ((aoff ^ ((k) << 6)) + (m) * 2048))
#define LDB(dst, dbuf, n, k) dst = *(const bf16x8*)(smem + (dbuf) * 32768 + ((boff ^ ((k) << 6)) + (n) * 2048))

#define LD_AF(dst, dbuf, mq)                               \
    LDA(dst[0][0], dbuf, 2*(mq),     0); LDA(dst[0][1], dbuf, 2*(mq),     1); \
    LDA(dst[1][0], dbuf, 2*(mq) + 1, 0); LDA(dst[1][1], dbuf, 2*(mq) + 1, 1)
#define LD_BF(dst, dbuf, kk)                               \
    LDB(dst[0][kk], dbuf, 0, kk); LDB(dst[1][kk], dbuf, 1, kk); \
    LDB(dst[2][kk], dbuf, 2, kk); LDB(dst[3][kk], dbuf, 3, kk)

#define BAR()                                              \
    __builtin_amdgcn_s_barrier();                          \
    __builtin_amdgcn_sched_barrier(0)

#define VMW(n) asm volatile("s_waitcnt vmcnt(" #n ")" ::: "memory")

#define MF16(afX, bfrX, q) do {                            \
    __builtin_amdgcn_s_setprio(1);                         \
    _Pragma("unroll")                                      \
    for (int ml = 0; ml < 2; ++ml)                         \
      _Pragma("unroll")                                    \
      for (int n_ = 0; n_ < 4; ++n_)                       \
        _Pragma("unroll")                                  \
        for (int k_ = 0; k_ < 2; ++k_)                     \
          acc[2*(q)+ml][n_] = __builtin_amdgcn_mfma_f32_16x16x32_bf16( \
              afX[ml][k_], bfrX[n_][k_], acc[2*(q)+ml][n_], 0, 0, 0);  \
    __builtin_amdgcn_s_setprio(0); } while (0)

    f32x4 zero = {0.f, 0.f, 0.f, 0.f};
    f32x4 acc[8][4];
#pragma unroll
    for (int m = 0; m < 8; ++m)
#pragma unroll
        for (int n = 0; n < 4; ++n) acc[m][n] = zero;

    const int NT = K >> 6;     // BK=64 tiles (even for all call sites)
    const int NI = NT >> 1;

    // prologue: tile0 A+B -> b0, tile1 B -> b1; confirm tile0 (leave B(1) in flight)
    STG_A(0, 0, 0); STG_A(0, 0, 1);
    STG_B(0, 0, 0); STG_B(0, 0, 1);
    STG_B(1, 1, 0); STG_B(1, 1, 1);
    VMW(4);
    BAR();
    // initial fragment prefetch (tile 0): bfr both k halves + af for ph1
    bf16x8 afA[2][2], afB[2][2], bfrA[4][2], bfrB[4][2];
    LD_BF(bfrA, 0, 0); LD_BF(bfrA, 0, 1);
    LD_AF(afA, 0, 0);

    for (int i = 0; i < NI; ++i) {
        const int T  = 2 * i;
        const int k2 = (T + 2 < NT) ? T + 2 : NT - 1;   // clamped source (dest dead on last iter)
        const int k3 = (T + 3 < NT) ? T + 3 : NT - 1;

        // ph1 — MFMA tile T q0; prefetch af(ph2)
        STG_A(1, T + 1, 0);
        LD_AF(afB, 0, 1);
        BAR(); MF16(afA, bfrA, 0); BAR();
        // ph2 — confirm B(T+1); prefetch af(ph3)
        STG_A(1, T + 1, 1);
        VMW(4);
        LD_AF(afA, 0, 2);
        BAR(); MF16(afB, bfrA, 1); BAR();
        // ph3 — confirm A(T+1); prefetch af(ph4) + bfr(T+1) k0 (B(T+1) ok since ph2)
        STG_B(0, k2, 0);
        VMW(2);
        LD_AF(afB, 0, 3);
        LD_BF(bfrB, 1, 0);
        BAR(); MF16(afA, bfrA, 2); BAR();
        // ph4 — prefetch af(ph5, tile T+1; A(T+1) ok since ph3) + bfr(T+1) k1
        STG_B(0, k2, 1);
        LD_AF(afA, 1, 0);
        LD_BF(bfrB, 1, 1);
        BAR(); MF16(afB, bfrA, 3); BAR();
        // ph5 — MFMA tile T+1 q0; prefetch af(ph6)
        STG_A(0, k2, 0);
        LD_AF(afB, 1, 1);
        BAR(); MF16(afA, bfrB, 0); BAR();
        // ph6 — confirm B(T+2); prefetch af(ph7)
        STG_A(0, k2, 1);
        VMW(4);
        LD_AF(afA, 1, 2);
        BAR(); MF16(afB, bfrB, 1); BAR();
        // ph7 — confirm A(T+2); prefetch af(ph8) + bfr(T+2) k0 (B(T+2) ok since ph6)
        STG_B(1, k3, 0);
        VMW(2);
        LD_AF(afB, 1, 3);
        LD_BF(bfrA, 0, 0);
        BAR(); MF16(afA, bfrB, 2); BAR();
        // ph8 — prefetch af(next ph1, tile T+2; A(T+2) ok since ph7) + bfr(T+2) k1
        STG_B(1, k3, 1);
        LD_AF(afA, 0, 0);
        LD_BF(bfrA, 0, 1);
        BAR(); MF16(afB, bfrB, 3); BAR();

        // ---- segment-boundary fold: acc *= ratT[p][row] (telescoping probs) ----
        if (((i + 1) & (TPS / 2 - 1)) == 0) {
            const int p = (i + 1) / (TPS / 2) - 1;     // 0..7
            const float* rp = ratT + (size_t)p * B_SZ + (m0 + wr * 128 + quad * 4);
            f32x4 rr[8];
#pragma unroll
            for (int m = 0; m < 8; ++m) rr[m] = *(const f32x4*)(rp + m * 16);
#pragma unroll
            for (int m = 0; m < 8; ++m)
#pragma unroll
                for (int n = 0; n < 4; ++n)
                    acc[m][n] *= rr[m];
        }
    }

    asm volatile("s_waitcnt vmcnt(0)" ::: "memory");  // drain trailing (dead) stages

    // epilogue: + Σ_p probs·bexp[p,:], ReLU, bf16 store
    const int colb = n0 + wc * 64 + l16;
    float bx[4][NP];
#pragma unroll
    for (int n = 0; n < 4; ++n)
#pragma unroll
        for (int p = 0; p < NP; ++p)
            bx[n][p] = bexp[(size_t)p * N + colb + n * 16];
#pragma unroll
    for (int m = 0; m < 8; ++m) {
#pragma unroll
        for (int r = 0; r < 4; ++r) {
            const int row = m0 + wr * 128 + m * 16 + quad * 4 + r;
            const float* pr = probs + (size_t)row * NP;
            f32x4 p0 = *(const f32x4*)pr;
            f32x4 p1 = *(const f32x4*)(pr + 4);
            float pv[NP] = {p0[0], p0[1], p0[2], p0[3], p1[0], p1[1], p1[2], p1[3]};
#pragma unroll
            for (int n = 0; n < 4; ++n) {
                float bsum = 0.f;
#pragma unroll
                for (int p = 0; p < NP; ++p) bsum += pv[p] * bx[n][p];
                float v = fmaxf(acc[m][n][r] + bsum, 0.f);
                C[(size_t)row * N + colb + n * 16] = __float2bfloat16(v);
            }
        }
    }
#undef STG_A
#undef STG_B
#undef LDA
#undef LDB
#undef LD_AF
#undef LD_BF
#undef BAR
#undef VMW
#undef MF16
}

// Plain C = A @ Bt^T + bias (f32 out) for the classifier. 128x128, dbuf, swizzled.
__global__ __launch_bounds__(256)
void gemm_bt_k(const __hip_bfloat16* __restrict__ A, const __hip_bfloat16* __restrict__ Bt,
               int M, int N, int K, const float* __restrict__ bias, float* __restrict__ C) {
    __shared__ alignas(16) __hip_bfloat16 As[2 * 128 * 32];
    __shared__ alignas(16) __hip_bfloat16 Bs[2 * 128 * 32];
    const int tid  = threadIdx.x;
    const int wid  = tid >> 6, lane = tid & 63;
    const int quad = lane >> 4, l16 = lane & 15;
    const int waveM = (wid >> 1) << 6, waveN = (wid & 1) << 6;
    const int m0 = blockIdx.x * 128, n0 = blockIdx.y * 128;

    f32x4 zero = {0.f, 0.f, 0.f, 0.f};
    f32x4 acc[4][4];
#pragma unroll
    for (int a = 0; a < 4; ++a)
#pragma unroll
        for (int b = 0; b < 4; ++b) acc[a][b] = zero;

    const int srow = tid >> 2;
    const int skc  = (((tid & 3) ^ (srow & 3) ^ ((srow >> 2) & 3)) << 3);
    const __hip_bfloat16* Ag = A  + (size_t)(m0 + srow) * K + skc;
    const __hip_bfloat16* Bg = Bt + (size_t)(n0 + srow) * K + skc;
    const size_t rowStep = (size_t)64 * K;
    __hip_bfloat16* AsB = As + wid * 512;
    __hip_bfloat16* BsB = Bs + wid * 512;
    const int csel = (quad ^ (l16 & 3) ^ ((l16 >> 2) & 3)) << 3;

    async_ld16(Ag,           AsB);
    async_ld16(Ag + rowStep, AsB + 2048);
    async_ld16(Bg,           BsB);
    async_ld16(Bg + rowStep, BsB + 2048);

    for (int kt = 0; kt < K; kt += 32) {
        const int cur = (kt >> 5) & 1;
        __syncthreads();
        if (kt + 32 < K) {
            const int nb = (1 - cur) * 4096;
            async_ld16(Ag + kt + 32,           AsB + nb);
            async_ld16(Ag + kt + 32 + rowStep, AsB + nb + 2048);
            async_ld16(Bg + kt + 32,           BsB + nb);
            async_ld16(Bg + kt + 32 + rowStep, BsB + nb + 2048);
        }
        const __hip_bfloat16* AsC = As + cur * 4096;
        const __hip_bfloat16* BsC = Bs + cur * 4096;
        bf16x8 af[4], bfr[4];
#pragma unroll
        for (int q = 0; q < 4; ++q) {
            af[q]  = *(const bf16x8*)(AsC + (waveM + q * 16 + l16) * 32 + csel);
            bfr[q] = *(const bf16x8*)(BsC + (waveN + q * 16 + l16) * 32 + csel);
        }
#pragma unroll
        for (int tm = 0; tm < 4; ++tm)
#pragma unroll
            for (int tn = 0; tn < 4; ++tn)
                acc[tm][tn] = __builtin_amdgcn_mfma_f32_16x16x32_bf16(
                    af[tm], bfr[tn], acc[tm][tn], 0, 0, 0);
    }

    const int colb = n0 + waveN + l16;
#pragma unroll
    for (int tm = 0; tm < 4; ++tm)
#pragma unroll
        for (int r = 0; r < 4; ++r) {
            int row = m0 + waveM + tm * 16 + quad * 4 + r;
#pragma unroll
            for (int tn = 0; tn < 4; ++tn)
                C[(size_t)row * N + colb + tn * 16] =
                    acc[tm][tn][r] + bias[colb + tn * 16];
        }
}

extern "C" void kernel_launch(void* const* d_in, const int* in_sizes, int n_in,
                              void* d_out, int out_size, void* d_ws, size_t ws_size,
                              hipStream_t stream) {
    const float* x   = (const float*)d_in[0];
    const float* W1  = (const float*)d_in[1];
    const float* b1  = (const float*)d_in[2];
    const float* S1  = (const float*)d_in[3];
    const float* sb1 = (const float*)d_in[4];
    const float* W2  = (const float*)d_in[5];
    const float* b2  = (const float*)d_in[6];
    const float* S2  = (const float*)d_in[7];
    const float* sb2 = (const float*)d_in[8];
    const float* Wc  = (const float*)d_in[9];
    const float* bc  = (const float*)d_in[10];
    float* out = (float*)d_out;

    char* ws = (char*)d_ws;
    size_t off = 0;
    auto alloc = [&](size_t bytes) {
        char* p = ws + off;
        off += (bytes + 255) & ~(size_t)255;
        return p;
    };
    __hip_bfloat16* W1t = (__hip_bfloat16*)alloc((size_t)H1_SZ * (NP * IN_SZ) * 2);  // 32 MB
    __hip_bfloat16* W2t = (__hip_bfloat16*)alloc((size_t)H2_SZ * (NP * H1_SZ) * 2);  // 64 MB
    __hip_bfloat16* Wct = (__hip_bfloat16*)alloc((size_t)OUT_SZ * H2_SZ * 2);        //  4 MB
    float* probs1       = (float*)alloc((size_t)B_SZ * NP * 4);
    float* probs2       = (float*)alloc((size_t)B_SZ * NP * 4);
    float* rat1         = (float*)alloc((size_t)NP * B_SZ * 4);
    float* rat2         = (float*)alloc((size_t)NP * B_SZ * 4);
    __hip_bfloat16* xbf = (__hip_bfloat16*)alloc((size_t)B_SZ * IN_SZ * 2);          // 16 MB
    __hip_bfloat16* h1  = (__hip_bfloat16*)alloc((size_t)B_SZ * H1_SZ * 2);          // 32 MB
    __hip_bfloat16* h2  = (__hip_bfloat16*)alloc((size_t)B_SZ * H2_SZ * 2);          // 32 MB

    // unified prep: W1t + W2t + Wct transposes + x cast in one dispatch
    const int nPrep = (H1_SZ / 32) * ((NP * IN_SZ) / 32)
                    + (H2_SZ / 32) * ((NP * H1_SZ) / 32)
                    + (OUT_SZ / 32) * (H2_SZ / 32)
                    + (B_SZ * IN_SZ) / (256 * 8);
    prep_k<<<nPrep, dim3(32, 8), 0, stream>>>(W1, W2, Wc, x, W1t, W2t, Wct, xbf);

    // layer 1 (TPS = IN/64 = 16)
    selector_k<float><<<B_SZ / 4, dim3(64, 4), 0, stream>>>(x, S1, sb1, probs1, rat1, IN_SZ);
    drn_gemm8_k<16><<<(B_SZ / 256) * (H1_SZ / 256), 512, 0, stream>>>(
        xbf, W1t, H1_SZ, NP * IN_SZ, IN_SZ, rat1, probs1, b1, h1);

    // layer 2 (TPS = H1/64 = 32)
    selector_k<__hip_bfloat16><<<B_SZ / 4, dim3(64, 4), 0, stream>>>(h1, S2, sb2, probs2, rat2, H1_SZ);
    drn_gemm8_k<32><<<(B_SZ / 256) * (H2_SZ / 256), 512, 0, stream>>>(
        h1, W2t, H2_SZ, NP * H1_SZ, H1_SZ, rat2, probs2, b2, h2);

    // classifier
    gemm_bt_k<<<dim3(B_SZ / 128, OUT_SZ / 128), 256, 0, stream>>>(
        h2, Wct, B_SZ, OUT_SZ, H2_SZ, bc, out);
}